// Round 2
// baseline (100.448 us; speedup 1.0000x reference)
//
#include <hip/hip_runtime.h>

#define NCH   10
#define NCODE 1024
#define NLOC  65536      // 16*64*64 locations
#define NZ    655360     // 16*10*64*64 elements of z / z_quantized
#define NBLK  128
#define BLOCK 128        // threads per block
#define ITERS 4          // location-chunks per block: 128*4*128 = 65536

__device__ __forceinline__ float wave_reduce_sum(float v) {
#pragma unroll
    for (int off = 32; off > 0; off >>= 1)
        v += __shfl_down(v, off, 64);
    return v;
}

// Kernel 1: per-location quantization + factored-softmax statistics.
// p_n(loc) = prod_c sigmoid(400 * z_c * s_{n,c}) -> outer product A[32] x B[32].
__global__ __launch_bounds__(BLOCK) void lfq_main(
    const float* __restrict__ z, float* __restrict__ out,
    float* __restrict__ wsP, float* __restrict__ wsC, float* __restrict__ wsE)
{
    // rotation-swizzled [loc][chunk] layout: chunk r of loc stored at (r+loc)&7
    __shared__ float4 sA4[BLOCK][8];
    __shared__ float4 sB4[BLOCK][8];

    const int tid = threadIdx.x;
    const int ca = tid & 7;       // logical A chunk (words 4*ca..4*ca+3)
    const int j0 = tid >> 3;      // logical B word, group 0
    const int j1 = 16 + j0;       // logical B word, group 1

    float commit = 0.f, ent = 0.f;
    float4 acc0 = {0.f,0.f,0.f,0.f}, acc1 = {0.f,0.f,0.f,0.f};

    for (int it = 0; it < ITERS; ++it) {
        const int loc = (blockIdx.x * ITERS + it) * BLOCK + tid;  // [0, 65536)
        const int b   = loc >> 12;                  // 4096 locations per image
        const int hw  = loc & 4095;
        const int base = b * (NCH * 4096) + hw;     // z[b][c][hw], ch stride 4096

        float p[NCH], q[NCH];
        int idx = 0;
#pragma unroll
        for (int c = 0; c < NCH; ++c) {
            float zc = z[base + c * 4096];
            bool bit = zc > 0.f;
            float s = bit ? 1.f : -1.f;
            out[base + c * 4096] = s;               // straight-through fwd value
            if (bit) idx += (1 << c);
            float d = s - zc;
            commit += d * d;
            // P(bit=1) = sigmoid(400*z); binary entropy, overflow-stable
            float a = fabsf(zc) * 400.f;
            float e = expf(-a);                     // underflow->0 for big a: ok
            float inv = 1.f / (1.f + e);
            ent += log1pf(e) + a * e * inv;
            p[c] = bit ? inv : e * inv;             // sigmoid(+x)/sigmoid(-x)
            q[c] = bit ? e * inv : inv;
        }
        out[NZ + 2 + loc] = (float)idx;             // indices as float (exact)

        // butterfly: A[j] = prod_{c<5} (bit_c(j)? p_c : q_c), B: channels 5..9.
        float A[32], B[32];
        A[0] = 1.f; B[0] = 1.f;
#pragma unroll
        for (int c = 0; c < 5; ++c) {
            const int chA = 4 - c;
            const int chB = 9 - c;
            const int len = 1 << c;
#pragma unroll
            for (int j = 15; j >= 0; --j) {
                if (j < len) {
                    float va = A[j];
                    A[2 * j + 1] = va * p[chA];
                    A[2 * j]     = va * q[chA];
                    float vb = B[j];
                    B[2 * j + 1] = vb * p[chB];
                    B[2 * j]     = vb * q[chB];
                }
            }
        }

        __syncthreads();   // protect LDS from previous iteration's phase-2 reads
#pragma unroll
        for (int r = 0; r < 8; ++r) {
            const int g = (r + tid) & 7;
            sA4[tid][g] = make_float4(A[4*r], A[4*r+1], A[4*r+2], A[4*r+3]);
            sB4[tid][g] = make_float4(B[4*r], B[4*r+1], B[4*r+2], B[4*r+3]);
        }
        __syncthreads();

        // phase 2: thread t accumulates codes {4t..4t+3} and {512+4t..512+4t+3}
        // over 128 locations: p_n(loc) = A_loc[n&31] * B_loc[n>>5]
#pragma unroll 4
        for (int l = 0; l < BLOCK; ++l) {
            float4 a = sA4[l][(ca + l) & 7];
            const float* b0p = (const float*)&sB4[l][((j0 >> 2) + l) & 7];
            const float* b1p = (const float*)&sB4[l][((j1 >> 2) + l) & 7];
            float b0 = b0p[j0 & 3];
            float b1 = b1p[j1 & 3];
            acc0.x += a.x * b0; acc0.y += a.y * b0; acc0.z += a.z * b0; acc0.w += a.w * b0;
            acc1.x += a.x * b1; acc1.y += a.y * b1; acc1.z += a.z * b1; acc1.w += a.w * b1;
        }
    }

    // block partial sums of commitment and per-sample entropy
    __syncthreads();        // phase-2 reads done; safe to alias LDS
    float cw = wave_reduce_sum(commit);
    float ew = wave_reduce_sum(ent);
    float* red = (float*)sA4;
    const int wave = tid >> 6;
    const int lane = tid & 63;
    if (lane == 0) { red[wave] = cw; red[4 + wave] = ew; }
    __syncthreads();
    if (tid == 0) {
        wsC[blockIdx.x] = red[0] + red[1];
        wsE[blockIdx.x] = red[4] + red[5];
    }

    float4* wp = (float4*)(wsP + blockIdx.x * NCODE);
    wp[tid] = acc0;           // codes 4t..4t+3
    wp[128 + tid] = acc1;     // codes 512+4t..515+4t
}

// Kernel 2: reduce partials -> avg_entropy, loss, per_sample_entropy
__global__ __launch_bounds__(1024) void lfq_reduce(
    const float* __restrict__ wsP, const float* __restrict__ wsC,
    const float* __restrict__ wsE, float* __restrict__ out)
{
    const int n = threadIdx.x;   // code id
    float s = 0.f;
    for (int bb = 0; bb < NBLK; ++bb) s += wsP[bb * NCODE + n];
    float avg_p = s * (1.f / (float)NLOC);
    float term = -avg_p * logf(avg_p + 1e-5f);
    float c = 0.f, e = 0.f;
    if (n < NBLK) { c = wsC[n]; e = wsE[n]; }
    float tw = wave_reduce_sum(term);
    float cw = wave_reduce_sum(c);
    float ew = wave_reduce_sum(e);
    __shared__ float red[48];
    const int wave = n >> 6, lane = n & 63;
    if (lane == 0) { red[wave] = tw; red[16 + wave] = cw; red[32 + wave] = ew; }
    __syncthreads();
    if (n == 0) {
        float avg_ent = 0.f, cs = 0.f, es = 0.f;
#pragma unroll
        for (int w = 0; w < 16; ++w) {
            avg_ent += red[w]; cs += red[16 + w]; es += red[32 + w];
        }
        float commitment = 0.25f * cs * (1.f / (float)NZ);
        float per_sample = es * (1.f / (float)NLOC);
        float entropy_loss = 0.1f * (per_sample - avg_ent);  // gamma = 1.0
        out[NZ] = commitment + entropy_loss;
        out[NZ + 1] = per_sample;
    }
}

extern "C" void kernel_launch(void* const* d_in, const int* in_sizes, int n_in,
                              void* d_out, int out_size, void* d_ws, size_t ws_size,
                              hipStream_t stream) {
    const float* z = (const float*)d_in[0];
    float* out = (float*)d_out;
    float* wsP = (float*)d_ws;               // [NBLK][1024] prob partial sums
    float* wsC = wsP + NBLK * NCODE;         // [NBLK] commitment partials
    float* wsE = wsC + NBLK;                 // [NBLK] entropy partials

    lfq_main<<<NBLK, BLOCK, 0, stream>>>(z, out, wsP, wsC, wsE);
    lfq_reduce<<<1, 1024, 0, stream>>>(wsP, wsC, wsE, out);
}

// Round 3
// 84.019 us; speedup vs baseline: 1.1955x; 1.1955x over previous
//
#include <hip/hip_runtime.h>

#define NCH     10
#define NCODE   1024
#define NLOC    65536      // 16*64*64 locations
#define NZ      655360     // 16*10*64*64 elements of z / z_quantized
#define K1_BLK  128
#define K1_THR  512        // 1 location per thread: 128*512 = 65536
#define K2_BLK  16         // 16 blocks x 64 codes = 1024 codes

__device__ __forceinline__ float wave_reduce_sum(float v) {
#pragma unroll
    for (int off = 32; off > 0; off >>= 1)
        v += __shfl_down(v, off, 64);
    return v;
}

// K1: streaming quantization + truncated factored-softmax histogram.
// p_n(loc) = pstar * prod_{c in flip(n)} exp(-400|z_c|); ratios < 1e-10 dropped.
__global__ __launch_bounds__(K1_THR) void lfq_main(
    const float* __restrict__ z, float* __restrict__ out,
    float* __restrict__ wsP, float* __restrict__ wsC, float* __restrict__ wsE)
{
    __shared__ float hist[NCODE];                  // 4 KB prob histogram
    __shared__ float sR[NCH][K1_THR];              // 20 KB small-channel ratios
    __shared__ unsigned short sM[NCH][K1_THR];     // 10 KB small-channel bitmasks
    __shared__ float red[16];

    const int tid = threadIdx.x;
    hist[tid] = 0.f; hist[tid + 512] = 0.f;
    __syncthreads();

    const int loc  = blockIdx.x * K1_THR + tid;    // [0, 65536)
    const int b    = loc >> 12;                    // 4096 locations per image
    const int base = b * (NCH * 4096) + (loc & 4095);  // z[b][c][hw], ch stride 4096

    float commit = 0.f, ent = 0.f, pstar = 1.f;
    int idx = 0, k = 0;
#pragma unroll
    for (int c = 0; c < NCH; ++c) {
        float zc = z[base + c * 4096];
        bool bit = zc > 0.f;
        float s = bit ? 1.f : -1.f;
        out[base + c * 4096] = s;                  // straight-through fwd value
        if (bit) idx |= (1 << c);
        float d = s - zc;
        commit += d * d;
        // P(bit matches sign) = sigmoid(a), a = 400|z|; overflow-stable entropy
        float a = fabsf(zc) * 400.f;
        float e = expf(-a);                        // flip ratio sig(-a)/sig(a)
        float inv = 1.f / (1.f + e);
        ent += log1pf(e) + a * e * inv;            // binary entropy (nats)
        pstar *= inv;                              // prob of the hard code
        if (a < 23.0f) {                           // ratio > ~1e-10: keep
            sR[k][tid] = e;
            sM[k][tid] = (unsigned short)(1u << c);
            ++k;
        }
    }
    out[NZ + 2 + loc] = (float)idx;                // indices as float (exact)

    // histogram: hard code + subsets of small channels (expected ~1.4 adds)
    atomicAdd(&hist[idx], pstar);
    if (k > 0) {
        for (int m = 1; m < (1 << k); ++m) {
            float w = pstar;
            int code = idx;
            for (int j = 0; j < k; ++j)
                if (m & (1 << j)) { w *= sR[j][tid]; code ^= sM[j][tid]; }
            atomicAdd(&hist[code], w);
        }
    }
    __syncthreads();

    // flush per-block histogram (coalesced float2: 512 threads x 8B)
    ((float2*)(wsP + blockIdx.x * NCODE))[tid] =
        make_float2(hist[2 * tid], hist[2 * tid + 1]);

    // block partials of commitment / per-sample entropy
    float cw = wave_reduce_sum(commit);
    float ew = wave_reduce_sum(ent);
    const int wave = tid >> 6, lane = tid & 63;
    if (lane == 0) { red[wave] = cw; red[8 + wave] = ew; }
    __syncthreads();
    if (tid == 0) {
        float cs = 0.f, es = 0.f;
#pragma unroll
        for (int w = 0; w < 8; ++w) { cs += red[w]; es += red[8 + w]; }
        wsC[blockIdx.x] = cs;
        wsE[blockIdx.x] = es;
    }
}

// K2: column-sum the 128 per-block histograms, entropy term per code,
// one partial sum per 64-code block.
__global__ __launch_bounds__(64) void lfq_hist_reduce(
    const float* __restrict__ wsP, float* __restrict__ wsS)
{
    const int code = blockIdx.x * 64 + threadIdx.x;
    float s = 0.f;
#pragma unroll 8
    for (int bb = 0; bb < K1_BLK; ++bb) s += wsP[bb * NCODE + code];
    float avg_p = s * (1.f / (float)NLOC);
    float term = -avg_p * logf(avg_p + 1e-5f);
    float t = wave_reduce_sum(term);
    if (threadIdx.x == 0) wsS[blockIdx.x] = t;
}

// K3: finalize scalars.
__global__ __launch_bounds__(128) void lfq_final(
    const float* __restrict__ wsC, const float* __restrict__ wsE,
    const float* __restrict__ wsS, float* __restrict__ out)
{
    const int t = threadIdx.x;     // 128 threads
    float c = wsC[t];
    float e = wsE[t];
    float s = (t < K2_BLK) ? wsS[t] : 0.f;
    float cw = wave_reduce_sum(c);
    float ew = wave_reduce_sum(e);
    float sw = wave_reduce_sum(s);
    __shared__ float red[6];
    const int wave = t >> 6, lane = t & 63;
    if (lane == 0) { red[wave] = cw; red[2 + wave] = ew; red[4 + wave] = sw; }
    __syncthreads();
    if (t == 0) {
        float cs = red[0] + red[1];
        float es = red[2] + red[3];
        float avg_ent = red[4] + red[5];
        float commitment = 0.25f * cs * (1.f / (float)NZ);
        float per_sample = es * (1.f / (float)NLOC);
        out[NZ]     = commitment + 0.1f * (per_sample - avg_ent);  // gamma=1
        out[NZ + 1] = per_sample;
    }
}

extern "C" void kernel_launch(void* const* d_in, const int* in_sizes, int n_in,
                              void* d_out, int out_size, void* d_ws, size_t ws_size,
                              hipStream_t stream) {
    const float* z = (const float*)d_in[0];
    float* out = (float*)d_out;
    float* wsP = (float*)d_ws;               // [128][1024] histogram partials
    float* wsC = wsP + K1_BLK * NCODE;       // [128] commitment partials
    float* wsE = wsC + K1_BLK;               // [128] entropy partials
    float* wsS = wsE + K1_BLK;               // [16]  entropy-term partials

    lfq_main<<<K1_BLK, K1_THR, 0, stream>>>(z, out, wsP, wsC, wsE);
    lfq_hist_reduce<<<K2_BLK, 64, 0, stream>>>(wsP, wsS);
    lfq_final<<<1, 128, 0, stream>>>(wsC, wsE, wsS, out);
}

// Round 4
// 75.142 us; speedup vs baseline: 1.3368x; 1.1181x over previous
//
#include <hip/hip_runtime.h>

#define NCH    10
#define NCODE  1024
#define NLOC   65536      // 16*64*64 locations
#define NZ     655360     // 16*10*64*64 elements of z / z_quantized
#define K1_BLK 256
#define K1_THR 256        // 1 location per thread: 256*256 = 65536
#define NHIST  4          // interleaved global histograms (atomic contention /4)

__device__ __forceinline__ float wave_reduce_sum(float v) {
#pragma unroll
    for (int off = 32; off > 0; off >>= 1)
        v += __shfl_down(v, off, 64);
    return v;
}

// K0: zero the 4 global histograms (ws is poisoned 0xAA before every launch)
__global__ __launch_bounds__(1024) void lfq_init(float* __restrict__ wsH) {
    wsH[blockIdx.x * 1024 + threadIdx.x] = 0.f;
}

// K1: streaming quantization + truncated factored-softmax scatter.
// p_n(loc) = pstar * prod_{c in flip(n)} exp(-400|z_c|); ratios < 1e-10 dropped
// (a = 400|z| >= 23 contributes < 2.6e-9 to any bin / entropy term).
__global__ __launch_bounds__(K1_THR) void lfq_main(
    const float* __restrict__ z, float* __restrict__ out,
    float* __restrict__ wsH, float* __restrict__ wsC, float* __restrict__ wsE)
{
    __shared__ float sR[NCH][K1_THR];              // small-channel flip ratios
    __shared__ unsigned short sM[NCH][K1_THR];     // small-channel bitmasks
    __shared__ float red[8];

    const int tid  = threadIdx.x;
    const int loc  = blockIdx.x * K1_THR + tid;    // [0, 65536)
    const int b    = loc >> 12;                    // 4096 locations per image
    const int base = b * (NCH * 4096) + (loc & 4095);  // ch stride 4096
    float* hist = wsH + (blockIdx.x & (NHIST - 1)) * NCODE;

    float commit = 0.f, ent = 0.f, pstar = 1.f;
    int idx = 0, k = 0;
#pragma unroll
    for (int c = 0; c < NCH; ++c) {
        float zc = z[base + c * 4096];
        bool bit = zc > 0.f;
        float s = bit ? 1.f : -1.f;
        out[base + c * 4096] = s;                  // straight-through fwd value
        if (bit) idx |= (1 << c);
        float d = s - zc;
        commit += d * d;
        float a = fabsf(zc) * 400.f;               // logit gap vs bit-flip
        if (a < 23.0f) {                           // flip ratio > ~1e-10: keep
            float e = __expf(-a);
            float inv = 1.f / (1.f + e);
            ent += __logf(1.f + e) + a * e * inv;  // binary entropy (nats)
            pstar *= inv;
            sR[k][tid] = e;
            sM[k][tid] = (unsigned short)(1u << c);
            ++k;
        }
        // a >= 23: inv ~ 1 (pstar unchanged), entropy term < 3e-9 (dropped)
    }
    out[NZ + 2 + loc] = (float)idx;                // indices as float (exact)

    // scatter: hard code + subsets of small channels (expected ~1.5 atomics)
    atomicAdd(&hist[idx], pstar);
    for (int m = 1; m < (1 << k); ++m) {
        float w = pstar;
        int code = idx;
        for (int j = 0; j < k; ++j)
            if (m & (1 << j)) { w *= sR[j][tid]; code ^= sM[j][tid]; }
        atomicAdd(&hist[code], w);
    }

    // block partials of commitment / per-sample entropy
    float cw = wave_reduce_sum(commit);
    float ew = wave_reduce_sum(ent);
    const int wave = tid >> 6, lane = tid & 63;
    if (lane == 0) { red[wave] = cw; red[4 + wave] = ew; }
    __syncthreads();
    if (tid == 0) {
        wsC[blockIdx.x] = red[0] + red[1] + red[2] + red[3];
        wsE[blockIdx.x] = red[4] + red[5] + red[6] + red[7];
    }
}

// K2: finalize — avg_probs entropy over 1024 codes + scalar reductions.
__global__ __launch_bounds__(1024) void lfq_final(
    const float* __restrict__ wsH, const float* __restrict__ wsC,
    const float* __restrict__ wsE, float* __restrict__ out)
{
    const int n = threadIdx.x;   // code id
    float s = wsH[n] + wsH[NCODE + n] + wsH[2 * NCODE + n] + wsH[3 * NCODE + n];
    float avg_p = s * (1.f / (float)NLOC);
    float term = -avg_p * __logf(avg_p + 1e-5f);
    float c = (n < K1_BLK) ? wsC[n] : 0.f;
    float e = (n < K1_BLK) ? wsE[n] : 0.f;
    float tw = wave_reduce_sum(term);
    float cw = wave_reduce_sum(c);
    float ew = wave_reduce_sum(e);
    __shared__ float red[48];
    const int wave = n >> 6, lane = n & 63;
    if (lane == 0) { red[wave] = tw; red[16 + wave] = cw; red[32 + wave] = ew; }
    __syncthreads();
    if (n == 0) {
        float avg_ent = 0.f, cs = 0.f, es = 0.f;
#pragma unroll
        for (int w = 0; w < 16; ++w) {
            avg_ent += red[w]; cs += red[16 + w]; es += red[32 + w];
        }
        float commitment = 0.25f * cs * (1.f / (float)NZ);
        float per_sample = es * (1.f / (float)NLOC);
        out[NZ]     = commitment + 0.1f * (per_sample - avg_ent);  // gamma=1
        out[NZ + 1] = per_sample;
    }
}

extern "C" void kernel_launch(void* const* d_in, const int* in_sizes, int n_in,
                              void* d_out, int out_size, void* d_ws, size_t ws_size,
                              hipStream_t stream) {
    const float* z = (const float*)d_in[0];
    float* out = (float*)d_out;
    float* wsH = (float*)d_ws;               // [4][1024] global histograms
    float* wsC = wsH + NHIST * NCODE;        // [256] commitment partials
    float* wsE = wsC + K1_BLK;               // [256] entropy partials

    lfq_init<<<NHIST, 1024, 0, stream>>>(wsH);
    lfq_main<<<K1_BLK, K1_THR, 0, stream>>>(z, out, wsH, wsC, wsE);
    lfq_final<<<1, 1024, 0, stream>>>(wsH, wsC, wsE, out);
}